// Round 4
// baseline (287.064 us; speedup 1.0000x reference)
//
#include <hip/hip_runtime.h>
#include <hip/hip_bf16.h>
#include <stdint.h>

#define E_EXP 8
#define TOK   4096
#define HD    768
#define FD    3072
#define BK    64
#define CAP   8320   // 8192 assignments + max per-expert tile padding

typedef __attribute__((ext_vector_type(8))) short bf16x8;
typedef __attribute__((ext_vector_type(4))) float f32x4;

__device__ __forceinline__ unsigned short f2bf(float f) {
  union { float f; unsigned u; } v; v.f = f;
  unsigned r = v.u + 0x7fffu + ((v.u >> 16) & 1u);
  return (unsigned short)(r >> 16);
}
__device__ __forceinline__ float bf2f(unsigned short u) {
  union { unsigned u; float f; } v; v.u = ((unsigned)u) << 16;
  return v.f;
}

__device__ __forceinline__ void gload_lds16(const void* g, void* l) {
  __builtin_amdgcn_global_load_lds(
      (const __attribute__((address_space(1))) unsigned int*)g,
      (__attribute__((address_space(3))) unsigned int*)l, 16, 0, 0);
}

// bijective XCD-chunking swizzle (m204): orig%8 = XCD, give each XCD a
// contiguous wgid range so neighboring tiles share L2.
__device__ __forceinline__ int xcd_swizzle(int orig, int nwg) {
  int xcd = orig & 7, base = orig >> 3;
  int q = nwg >> 3, r = nwg & 7;
  return (xcd < r ? xcd * (q + 1) : r * (q + 1) + (xcd - r) * q) + base;
}

// ---------------- router: scores, softmax, top-2, x->bf16; NO atomics ----------
__global__ __launch_bounds__(256) void router_kernel(
    const float* __restrict__ x, const float* __restrict__ rw,
    const float* __restrict__ rb, unsigned short* __restrict__ xb,
    float* __restrict__ probs, int* __restrict__ ids,
    float* __restrict__ gates)
{
  __shared__ float lrw[E_EXP * HD];   // [e][h]
  for (int i = threadIdx.x; i < E_EXP * HD; i += 256) {
    int h = i >> 3, e = i & 7;
    lrw[e * HD + h] = rw[i];
  }
  __syncthreads();
  const int wave = threadIdx.x >> 6, lane = threadIdx.x & 63;
  const int t = blockIdx.x * 4 + wave;
  const float* xrow = x + (size_t)t * HD;
  float acc[8] = {0, 0, 0, 0, 0, 0, 0, 0};
#pragma unroll
  for (int i = 0; i < HD / 64; ++i) {
    int h = i * 64 + lane;
    float xv = xrow[h];
    xb[(size_t)t * HD + h] = f2bf(xv);
#pragma unroll
    for (int e = 0; e < 8; ++e) acc[e] += xv * lrw[e * HD + h];
  }
#pragma unroll
  for (int d = 1; d < 64; d <<= 1) {
#pragma unroll
    for (int e = 0; e < 8; ++e) acc[e] += __shfl_xor(acc[e], d);
  }
  if (lane == 0) {
    float p[8]; float m = -1e30f, sum = 0.f;
#pragma unroll
    for (int e = 0; e < 8; ++e) { p[e] = acc[e] + rb[e]; m = fmaxf(m, p[e]); }
#pragma unroll
    for (int e = 0; e < 8; ++e) { p[e] = __expf(p[e] - m); sum += p[e]; }
    float inv = 1.f / sum;
#pragma unroll
    for (int e = 0; e < 8; ++e) p[e] *= inv;
    int i1 = 0;
#pragma unroll
    for (int e = 1; e < 8; ++e) if (p[e] > p[i1]) i1 = e;   // ties -> lower idx
    int i2 = (i1 == 0) ? 1 : 0;
#pragma unroll
    for (int e = 0; e < 8; ++e) if (e != i1 && p[e] > p[i2]) i2 = e;
    ids[t * 2] = i1; ids[t * 2 + 1] = i2;
    float den = 1.f / (p[i1] + p[i2] + 1e-9f);
    gates[t * 2] = p[i1] * den; gates[t * 2 + 1] = p[i2] * den;
#pragma unroll
    for (int e = 0; e < 8; ++e) probs[t * 8 + e] = p[e];
  }
}

// ---------------- weight transpose: W[e][Kd][Nd] f32 -> Wt[e][Nd][Kd] bf16 ------
__global__ __launch_bounds__(256) void transpose_kernel(
    const float* __restrict__ W, unsigned short* __restrict__ Wt,
    int Kd, int Nd)
{
  __shared__ float tile[32][33];
  const int e = blockIdx.z;
  const int n0 = blockIdx.x * 32, k0 = blockIdx.y * 32;
  const int ci = threadIdx.x & 31, ri = threadIdx.x >> 5;
  const float* src = W + ((size_t)e * Kd + k0) * Nd + n0;
#pragma unroll
  for (int i = 0; i < 32; i += 8)
    tile[ri + i][ci] = src[(size_t)(ri + i) * Nd + ci];
  __syncthreads();
  unsigned short* dst = Wt + ((size_t)e * Nd + n0) * Kd + k0;
  const int co = (threadIdx.x & 15) * 2, ro = threadIdx.x >> 4;
#pragma unroll
  for (int i = 0; i < 32; i += 16) {
    int r = ro + i;
    unsigned v = (unsigned)f2bf(tile[co][r]) | ((unsigned)f2bf(tile[co + 1][r]) << 16);
    *(unsigned*)&dst[(size_t)r * Kd + co] = v;
  }
}

// ---------------- stats: counts, probs_sum, bases, tile maps, bal loss ----------
__global__ __launch_bounds__(256) void stats_kernel(
    const int* __restrict__ ids, const float* __restrict__ probs,
    int* __restrict__ meta, float* __restrict__ loss_out)
{
  __shared__ int cnt[8], top1c[8];
  __shared__ float wsum[4][8];
  if (threadIdx.x < 8) { cnt[threadIdx.x] = 0; top1c[threadIdx.x] = 0; }
  __syncthreads();
  float local[8] = {0, 0, 0, 0, 0, 0, 0, 0};
  for (int t = threadIdx.x; t < TOK; t += 256) {
    int e0 = ids[2 * t], e1 = ids[2 * t + 1];
    atomicAdd(&cnt[e0], 1); atomicAdd(&cnt[e1], 1); atomicAdd(&top1c[e0], 1);
    const float4* pr = (const float4*)&probs[(size_t)t * 8];
    float4 a = pr[0], b = pr[1];
    local[0] += a.x; local[1] += a.y; local[2] += a.z; local[3] += a.w;
    local[4] += b.x; local[5] += b.y; local[6] += b.z; local[7] += b.w;
  }
#pragma unroll
  for (int d = 1; d < 64; d <<= 1) {
#pragma unroll
    for (int e = 0; e < 8; ++e) local[e] += __shfl_xor(local[e], d);
  }
  const int wave = threadIdx.x >> 6, lane = threadIdx.x & 63;
  if (lane == 0) {
#pragma unroll
    for (int e = 0; e < 8; ++e) wsum[wave][e] = local[e];
  }
  __syncthreads();
  if (threadIdx.x == 0) {
    int total = 0, nt1 = 0, nt2 = 0;
    for (int e = 0; e < 8; ++e) {
      int c = cnt[e];
      meta[e] = c;
      meta[16 + e] = total;                     // base
      int t1 = (c + 127) >> 7;
      for (int i = 0; i < t1; ++i) { meta[64 + nt1 * 2] = e; meta[64 + nt1 * 2 + 1] = total + i * 128; ++nt1; }
      int t2 = (c + 63) >> 6;
      for (int i = 0; i < t2; ++i) { meta[256 + nt2 * 2] = e; meta[256 + nt2 * 2 + 1] = total + i * 64; ++nt2; }
      total += c;
    }
    meta[32] = nt1; meta[33] = nt2;
    float loss = 0.f;
    for (int e = 0; e < 8; ++e) {
      float psum = wsum[0][e] + wsum[1][e] + wsum[2][e] + wsum[3][e];
      loss += ((float)top1c[e] / 4096.f) * (psum / 4096.f);
    }
    loss_out[0] = 0.001f * loss;
  }
}

// ---------------- scatter: block-aggregated; records pos for combine -----------
__global__ __launch_bounds__(256) void scatter_kernel(
    const int* __restrict__ ids, int* __restrict__ meta,
    int* __restrict__ token_list, int* __restrict__ pos_list)
{
  __shared__ int lcnt[8];
  __shared__ int lbase[8];
  if (threadIdx.x < 8) lcnt[threadIdx.x] = 0;
  __syncthreads();
  const int t = blockIdx.x * 256 + threadIdx.x;
  const int e0 = ids[t * 2], e1 = ids[t * 2 + 1];
  const int s0 = atomicAdd(&lcnt[e0], 1);
  const int s1 = atomicAdd(&lcnt[e1], 1);
  __syncthreads();
  if (threadIdx.x < 8)
    lbase[threadIdx.x] = atomicAdd(&meta[24 + threadIdx.x], lcnt[threadIdx.x]);
  __syncthreads();
  int p0 = meta[16 + e0] + lbase[e0] + s0;
  int p1 = meta[16 + e1] + lbase[e1] + s1;
  token_list[p0] = t; pos_list[t * 2] = p0;
  token_list[p1] = t; pos_list[t * 2 + 1] = p1;
}

// ---------------- grouped GEMM (MODE 0: x@w1 + relu^2 -> h1 bf16;
//                  MODE 1: h1@w2 + b2 -> h2 bf16 rows) -------------------------
// 1-D grid, n-fastest tile order + bijective XCD chunking: consecutive wgids on
// one XCD share the A-panel (L2-resident) and mostly one expert's B panels.
// LDS: linear rows of BK=64 bf16; 16B k-chunks XOR-swizzled by (row&7) on BOTH
// the global source address (staging) and the ds_read address (rule 21).
template<int BM, int BN, int MODE>
__global__ __launch_bounds__(256) void moe_gemm(
    const unsigned short* __restrict__ A,
    const unsigned short* __restrict__ Bw,   // [E][NN][Kdim] bf16 (pre-transposed)
    const float* __restrict__ bias,          // [E][NN]
    const int* __restrict__ token_list,
    const int* __restrict__ meta,
    unsigned short* __restrict__ Cout,       // MODE0: h1[CAP][FD]; MODE1: h2[CAP][HD]
    const int Kdim, const int NN)
{
  const int NY = NN / BN;
  const int wgid = xcd_swizzle(blockIdx.x, gridDim.x);
  const int mt = wgid / NY;
  const int ny = wgid - mt * NY;
  const int nt_total = meta[32 + MODE];
  if (mt >= nt_total) return;
  const int* tmap = meta + (MODE == 0 ? 64 : 256);
  const int e = tmap[mt * 2], arow0 = tmap[mt * 2 + 1];
  const int ne_end = meta[16 + e] + meta[e];
  const int n0 = ny * BN;

  __shared__ unsigned short lA[BM * BK];
  __shared__ unsigned short lB[BN * BK];

  const int tid = threadIdx.x;
  const int wave = tid >> 6, lane = tid & 63;
  const int wr = wave >> 1, wc = wave & 1;
  constexpr int FM = BM / 32, FN = BN / 32;
  constexpr int NCA = BM / 32;   // A 1KB-chunks per wave
  constexpr int NCB = BN / 32;   // B chunks per wave

  // swizzled k-offset for staging: logical chunk (lane&7) XOR row-in-8 (lane>>3)&7
  const int kswz = ((lane & 7) ^ ((lane >> 3) & 7)) * 8;

  size_t aSrc[NCA];
#pragma unroll
  for (int i = 0; i < NCA; ++i) {
    int c = wave + i * 4;
    int r = c * 8 + (lane >> 3);
    int grow = (MODE == 0) ? token_list[arow0 + r] : (arow0 + r);
    aSrc[i] = (size_t)grow * Kdim + kswz;
  }
  size_t bSrc[NCB];
#pragma unroll
  for (int i = 0; i < NCB; ++i) {
    int c = wave + i * 4;
    int n = n0 + c * 8 + (lane >> 3);
    bSrc[i] = ((size_t)e * NN + n) * Kdim + kswz;
  }

  f32x4 acc[FM][FN] = {};

  for (int k0 = 0; k0 < Kdim; k0 += BK) {
#pragma unroll
    for (int i = 0; i < NCA; ++i)
      gload_lds16(A + aSrc[i] + k0, &lA[(wave + i * 4) * 512]);
#pragma unroll
    for (int i = 0; i < NCB; ++i)
      gload_lds16(Bw + bSrc[i] + k0, &lB[(wave + i * 4) * 512]);
    __syncthreads();
#pragma unroll
    for (int kk = 0; kk < BK; kk += 32) {
      bf16x8 af[FM], bfr[FN];
      const int lc = (kk >> 3) + (lane >> 4);   // logical 16B-chunk index 0..7
#pragma unroll
      for (int m2 = 0; m2 < FM; ++m2) {
        int row = wr * (BM / 2) + m2 * 16 + (lane & 15);
        af[m2] = *(const bf16x8*)&lA[row * BK + ((lc ^ (row & 7)) << 3)];
      }
#pragma unroll
      for (int n2 = 0; n2 < FN; ++n2) {
        int row = wc * (BN / 2) + n2 * 16 + (lane & 15);
        bfr[n2] = *(const bf16x8*)&lB[row * BK + ((lc ^ (row & 7)) << 3)];
      }
#pragma unroll
      for (int m2 = 0; m2 < FM; ++m2)
#pragma unroll
        for (int n2 = 0; n2 < FN; ++n2)
          acc[m2][n2] = __builtin_amdgcn_mfma_f32_16x16x32_bf16(
              af[m2], bfr[n2], acc[m2][n2], 0, 0, 0);
    }
    __syncthreads();
  }

  const float* be = bias + (size_t)e * NN;
#pragma unroll
  for (int m2 = 0; m2 < FM; ++m2) {
    const int lr = wr * (BM / 2) + m2 * 16 + (lane >> 4) * 4;
#pragma unroll
    for (int n2 = 0; n2 < FN; ++n2) {
      const int col = n0 + wc * (BN / 2) + n2 * 16 + (lane & 15);
      const float bv = be[col];
#pragma unroll
      for (int j = 0; j < 4; ++j) {
        const int arow = arow0 + lr + j;
        if (arow < ne_end) {
          float v = acc[m2][n2][j] + bv;
          if (MODE == 0) { v = fmaxf(v, 0.f); v = v * v; }
          Cout[(size_t)arow * NN + col] = f2bf(v);
        }
      }
    }
  }
}

// ---------------- combine: out[t] = g0*h2[p0] + g1*h2[p1] ----------------------
__global__ __launch_bounds__(256) void combine_kernel(
    const unsigned short* __restrict__ h2, const int* __restrict__ pos_list,
    const float* __restrict__ gates, float* __restrict__ out)
{
  const int wave = threadIdx.x >> 6, lane = threadIdx.x & 63;
  const int t = blockIdx.x * 4 + wave;
  const int p0 = pos_list[2 * t], p1 = pos_list[2 * t + 1];
  const float g0 = gates[2 * t], g1 = gates[2 * t + 1];
  const unsigned short* r0 = h2 + (size_t)p0 * HD;
  const unsigned short* r1 = h2 + (size_t)p1 * HD;
  float* o = out + (size_t)t * HD;
#pragma unroll
  for (int i = 0; i < 3; ++i) {
    int h = i * 256 + lane * 4;
    ushort4 a = *(const ushort4*)&r0[h];
    ushort4 b = *(const ushort4*)&r1[h];
    float4 o4;
    o4.x = g0 * bf2f(a.x) + g1 * bf2f(b.x);
    o4.y = g0 * bf2f(a.y) + g1 * bf2f(b.y);
    o4.z = g0 * bf2f(a.z) + g1 * bf2f(b.z);
    o4.w = g0 * bf2f(a.w) + g1 * bf2f(b.w);
    *(float4*)&o[h] = o4;
  }
}

// -------------------------------- launch ---------------------------------------
extern "C" void kernel_launch(void* const* d_in, const int* in_sizes, int n_in,
                              void* d_out, int out_size, void* d_ws, size_t ws_size,
                              hipStream_t stream)
{
  (void)in_sizes; (void)n_in; (void)ws_size; (void)out_size;
  const float* x  = (const float*)d_in[0];
  const float* rw = (const float*)d_in[1];
  const float* rb = (const float*)d_in[2];
  const float* w1 = (const float*)d_in[3];
  const float* b1 = (const float*)d_in[4];
  const float* w2 = (const float*)d_in[5];
  const float* b2 = (const float*)d_in[6];
  float* out = (float*)d_out;

  char* ws = (char*)d_ws;
  size_t off = 0;
  auto alloc = [&](size_t bytes) {
    off = (off + 255) & ~(size_t)255;
    void* p = ws + off;
    off += bytes;
    return p;
  };
  unsigned short* xb  = (unsigned short*)alloc((size_t)TOK * HD * 2);
  unsigned short* w1t = (unsigned short*)alloc((size_t)E_EXP * FD * HD * 2);
  unsigned short* w2t = (unsigned short*)alloc((size_t)E_EXP * HD * FD * 2);
  unsigned short* h1  = (unsigned short*)alloc((size_t)CAP * FD * 2);
  unsigned short* h2  = (unsigned short*)alloc((size_t)CAP * HD * 2);
  int*   token_list = (int*)alloc(CAP * 4);
  int*   pos_list   = (int*)alloc((size_t)TOK * 2 * 4);
  int*   ids        = (int*)alloc((size_t)TOK * 2 * 4);
  float* gates      = (float*)alloc((size_t)TOK * 2 * 4);
  float* probs      = (float*)alloc((size_t)TOK * 8 * 4);
  int*   meta       = (int*)alloc(1024 * 4);
  char*  ctrl       = (char*)token_list;
  size_t ctrl_bytes = (ws + off) - ctrl;

  hipMemsetAsync(ctrl, 0, ctrl_bytes, stream);

  router_kernel<<<TOK / 4, 256, 0, stream>>>(x, rw, rb, xb, probs, ids, gates);
  transpose_kernel<<<dim3(FD / 32, HD / 32, E_EXP), 256, 0, stream>>>(w1, w1t, HD, FD);
  transpose_kernel<<<dim3(HD / 32, FD / 32, E_EXP), 256, 0, stream>>>(w2, w2t, FD, HD);
  stats_kernel<<<1, 256, 0, stream>>>(ids, probs, meta, out + (size_t)TOK * HD);
  scatter_kernel<<<TOK / 256, 256, 0, stream>>>(ids, meta, token_list, pos_list);
  // GEMM1: 71 max m-tiles x 12 n-tiles, n-fastest + XCD chunking
  moe_gemm<128, 256, 0><<<71 * (FD / 256), 256, 0, stream>>>(
      xb, w1t, b1, token_list, meta, h1, HD, FD);
  // GEMM2: 135 max m-tiles x 3 n-tiles
  moe_gemm<64, 256, 1><<<135 * (HD / 256), 256, 0, stream>>>(
      h1, w2t, b2, token_list, meta, h2, FD, HD);
  combine_kernel<<<TOK / 4, 256, 0, stream>>>(h2, pos_list, gates, out);
}

// Round 5
// 212.524 us; speedup vs baseline: 1.3507x; 1.3507x over previous
//
#include <hip/hip_runtime.h>
#include <hip/hip_bf16.h>
#include <stdint.h>

#define E_EXP 8
#define TOK   4096
#define HD    768
#define FD    3072
#define BK    64
#define CAP   8320   // 8192 assignments + max per-expert tile padding

typedef __attribute__((ext_vector_type(8))) short bf16x8;
typedef __attribute__((ext_vector_type(4))) float f32x4;

__device__ __forceinline__ unsigned short f2bf(float f) {
  union { float f; unsigned u; } v; v.f = f;
  unsigned r = v.u + 0x7fffu + ((v.u >> 16) & 1u);
  return (unsigned short)(r >> 16);
}
__device__ __forceinline__ float bf2f(unsigned short u) {
  union { unsigned u; float f; } v; v.u = ((unsigned)u) << 16;
  return v.f;
}

__device__ __forceinline__ void gload_lds16(const void* g, void* l) {
  __builtin_amdgcn_global_load_lds(
      (const __attribute__((address_space(1))) unsigned int*)g,
      (__attribute__((address_space(3))) unsigned int*)l, 16, 0, 0);
}

// bijective XCD-chunking swizzle (m204): orig%8 = XCD, give each XCD a
// contiguous wgid range so neighboring tiles share L2.
__device__ __forceinline__ int xcd_swizzle(int orig, int nwg) {
  int xcd = orig & 7, base = orig >> 3;
  int q = nwg >> 3, r = nwg & 7;
  return (xcd < r ? xcd * (q + 1) : r * (q + 1) + (xcd - r) * q) + base;
}

// ---------------- router: scores, softmax, top-2, x->bf16; NO atomics ----------
__global__ __launch_bounds__(256) void router_kernel(
    const float* __restrict__ x, const float* __restrict__ rw,
    const float* __restrict__ rb, unsigned short* __restrict__ xb,
    float* __restrict__ probs, int* __restrict__ ids,
    float* __restrict__ gates)
{
  __shared__ float lrw[E_EXP * HD];   // [e][h]
  for (int i = threadIdx.x; i < E_EXP * HD; i += 256) {
    int h = i >> 3, e = i & 7;
    lrw[e * HD + h] = rw[i];
  }
  __syncthreads();
  const int wave = threadIdx.x >> 6, lane = threadIdx.x & 63;
  const int t = blockIdx.x * 4 + wave;
  const float* xrow = x + (size_t)t * HD;
  float acc[8] = {0, 0, 0, 0, 0, 0, 0, 0};
#pragma unroll
  for (int i = 0; i < HD / 64; ++i) {
    int h = i * 64 + lane;
    float xv = xrow[h];
    xb[(size_t)t * HD + h] = f2bf(xv);
#pragma unroll
    for (int e = 0; e < 8; ++e) acc[e] += xv * lrw[e * HD + h];
  }
#pragma unroll
  for (int d = 1; d < 64; d <<= 1) {
#pragma unroll
    for (int e = 0; e < 8; ++e) acc[e] += __shfl_xor(acc[e], d);
  }
  if (lane == 0) {
    float p[8]; float m = -1e30f, sum = 0.f;
#pragma unroll
    for (int e = 0; e < 8; ++e) { p[e] = acc[e] + rb[e]; m = fmaxf(m, p[e]); }
#pragma unroll
    for (int e = 0; e < 8; ++e) { p[e] = __expf(p[e] - m); sum += p[e]; }
    float inv = 1.f / sum;
#pragma unroll
    for (int e = 0; e < 8; ++e) p[e] *= inv;
    int i1 = 0;
#pragma unroll
    for (int e = 1; e < 8; ++e) if (p[e] > p[i1]) i1 = e;   // ties -> lower idx
    int i2 = (i1 == 0) ? 1 : 0;
#pragma unroll
    for (int e = 0; e < 8; ++e) if (e != i1 && p[e] > p[i2]) i2 = e;
    ids[t * 2] = i1; ids[t * 2 + 1] = i2;
    float den = 1.f / (p[i1] + p[i2] + 1e-9f);
    gates[t * 2] = p[i1] * den; gates[t * 2 + 1] = p[i2] * den;
#pragma unroll
    for (int e = 0; e < 8; ++e) probs[t * 8 + e] = p[e];
  }
}

// ---------------- weight transpose: W[e][Kd][Nd] f32 -> Wt[e][Nd][Kd] bf16 ------
__global__ __launch_bounds__(256) void transpose_kernel(
    const float* __restrict__ W, unsigned short* __restrict__ Wt,
    int Kd, int Nd)
{
  __shared__ float tile[32][33];
  const int e = blockIdx.z;
  const int n0 = blockIdx.x * 32, k0 = blockIdx.y * 32;
  const int ci = threadIdx.x & 31, ri = threadIdx.x >> 5;
  const float* src = W + ((size_t)e * Kd + k0) * Nd + n0;
#pragma unroll
  for (int i = 0; i < 32; i += 8)
    tile[ri + i][ci] = src[(size_t)(ri + i) * Nd + ci];
  __syncthreads();
  unsigned short* dst = Wt + ((size_t)e * Nd + n0) * Kd + k0;
  const int co = (threadIdx.x & 15) * 2, ro = threadIdx.x >> 4;
#pragma unroll
  for (int i = 0; i < 32; i += 16) {
    int r = ro + i;
    unsigned v = (unsigned)f2bf(tile[co][r]) | ((unsigned)f2bf(tile[co + 1][r]) << 16);
    *(unsigned*)&dst[(size_t)r * Kd + co] = v;
  }
}

// ---------------- stats: counts, probs_sum, bases, tile maps, bal loss ----------
__global__ __launch_bounds__(256) void stats_kernel(
    const int* __restrict__ ids, const float* __restrict__ probs,
    int* __restrict__ meta, float* __restrict__ loss_out)
{
  __shared__ int cnt[8], top1c[8];
  __shared__ float wsum[4][8];
  if (threadIdx.x < 8) { cnt[threadIdx.x] = 0; top1c[threadIdx.x] = 0; }
  __syncthreads();
  float local[8] = {0, 0, 0, 0, 0, 0, 0, 0};
  for (int t = threadIdx.x; t < TOK; t += 256) {
    int e0 = ids[2 * t], e1 = ids[2 * t + 1];
    atomicAdd(&cnt[e0], 1); atomicAdd(&cnt[e1], 1); atomicAdd(&top1c[e0], 1);
    const float4* pr = (const float4*)&probs[(size_t)t * 8];
    float4 a = pr[0], b = pr[1];
    local[0] += a.x; local[1] += a.y; local[2] += a.z; local[3] += a.w;
    local[4] += b.x; local[5] += b.y; local[6] += b.z; local[7] += b.w;
  }
#pragma unroll
  for (int d = 1; d < 64; d <<= 1) {
#pragma unroll
    for (int e = 0; e < 8; ++e) local[e] += __shfl_xor(local[e], d);
  }
  const int wave = threadIdx.x >> 6, lane = threadIdx.x & 63;
  if (lane == 0) {
#pragma unroll
    for (int e = 0; e < 8; ++e) wsum[wave][e] = local[e];
  }
  __syncthreads();
  if (threadIdx.x == 0) {
    int total = 0, nt1 = 0, nt2 = 0;
    for (int e = 0; e < 8; ++e) {
      int c = cnt[e];
      meta[e] = c;
      meta[16 + e] = total;                     // base
      int t1 = (c + 127) >> 7;
      for (int i = 0; i < t1; ++i) { meta[64 + nt1 * 2] = e; meta[64 + nt1 * 2 + 1] = total + i * 128; ++nt1; }
      int t2 = (c + 63) >> 6;
      for (int i = 0; i < t2; ++i) { meta[256 + nt2 * 2] = e; meta[256 + nt2 * 2 + 1] = total + i * 64; ++nt2; }
      total += c;
    }
    meta[32] = nt1; meta[33] = nt2;
    float loss = 0.f;
    for (int e = 0; e < 8; ++e) {
      float psum = wsum[0][e] + wsum[1][e] + wsum[2][e] + wsum[3][e];
      loss += ((float)top1c[e] / 4096.f) * (psum / 4096.f);
    }
    loss_out[0] = 0.001f * loss;
  }
}

// ---------------- scatter: block-aggregated; records pos for combine -----------
__global__ __launch_bounds__(256) void scatter_kernel(
    const int* __restrict__ ids, int* __restrict__ meta,
    int* __restrict__ token_list, int* __restrict__ pos_list)
{
  __shared__ int lcnt[8];
  __shared__ int lbase[8];
  if (threadIdx.x < 8) lcnt[threadIdx.x] = 0;
  __syncthreads();
  const int t = blockIdx.x * 256 + threadIdx.x;
  const int e0 = ids[t * 2], e1 = ids[t * 2 + 1];
  const int s0 = atomicAdd(&lcnt[e0], 1);
  const int s1 = atomicAdd(&lcnt[e1], 1);
  __syncthreads();
  if (threadIdx.x < 8)
    lbase[threadIdx.x] = atomicAdd(&meta[24 + threadIdx.x], lcnt[threadIdx.x]);
  __syncthreads();
  int p0 = meta[16 + e0] + lbase[e0] + s0;
  int p1 = meta[16 + e1] + lbase[e1] + s1;
  token_list[p0] = t; pos_list[t * 2] = p0;
  token_list[p1] = t; pos_list[t * 2 + 1] = p1;
}

// ---------------- grouped GEMM (MODE 0: x@w1 + relu^2 -> h1 bf16;
//                  MODE 1: h1@w2 + b2 -> h2 bf16 rows) -------------------------
// NW waves per block (NW*64 threads). Wave grid: 2 x (NW/2); per-wave output
// (BM/2) x (BN/(NW/2)). 1-D grid, n-fastest + bijective XCD chunking.
// LDS: linear rows of BK=64 bf16; 16B k-chunks XOR-swizzled by (row&7) on BOTH
// the global source address (staging) and the ds_read address (rule 21).
template<int BM, int BN, int MODE, int NW>
__global__ __launch_bounds__(NW * 64, NW == 8 ? 4 : 3) void moe_gemm(
    const unsigned short* __restrict__ A,
    const unsigned short* __restrict__ Bw,   // [E][NN][Kdim] bf16 (pre-transposed)
    const float* __restrict__ bias,          // [E][NN]
    const int* __restrict__ token_list,
    const int* __restrict__ meta,
    unsigned short* __restrict__ Cout,       // MODE0: h1[CAP][FD]; MODE1: h2[CAP][HD]
    const int Kdim, const int NN)
{
  const int NY = NN / BN;
  const int wgid = xcd_swizzle(blockIdx.x, gridDim.x);
  const int mt = wgid / NY;
  const int ny = wgid - mt * NY;
  const int nt_total = meta[32 + MODE];
  if (mt >= nt_total) return;
  const int* tmap = meta + (MODE == 0 ? 64 : 256);
  const int e = tmap[mt * 2], arow0 = tmap[mt * 2 + 1];
  const int ne_end = meta[16 + e] + meta[e];
  const int n0 = ny * BN;

  __shared__ unsigned short lA[BM * BK];
  __shared__ unsigned short lB[BN * BK];

  const int tid = threadIdx.x;
  const int wave = tid >> 6, lane = tid & 63;
  constexpr int WC_N = NW / 2;              // waves along N
  const int wr = wave / WC_N, wc = wave % WC_N;
  constexpr int WROWS = BM / 2;             // per-wave rows
  constexpr int WCOLS = BN / WC_N;          // per-wave cols
  constexpr int FM = WROWS / 16, FN = WCOLS / 16;
  constexpr int NCA = (BM / 8) / NW;        // A 1KB-chunks per wave
  constexpr int NCB = (BN / 8) / NW;        // B chunks per wave

  // swizzled k-offset for staging: logical chunk (lane&7) XOR row-in-8 (lane>>3)&7
  const int kswz = ((lane & 7) ^ ((lane >> 3) & 7)) * 8;

  size_t aSrc[NCA];
#pragma unroll
  for (int i = 0; i < NCA; ++i) {
    int c = wave + i * NW;
    int r = c * 8 + (lane >> 3);
    int grow = (MODE == 0) ? token_list[arow0 + r] : (arow0 + r);
    aSrc[i] = (size_t)grow * Kdim + kswz;
  }
  size_t bSrc[NCB];
#pragma unroll
  for (int i = 0; i < NCB; ++i) {
    int c = wave + i * NW;
    int n = n0 + c * 8 + (lane >> 3);
    bSrc[i] = ((size_t)e * NN + n) * Kdim + kswz;
  }

  f32x4 acc[FM][FN] = {};

  for (int k0 = 0; k0 < Kdim; k0 += BK) {
#pragma unroll
    for (int i = 0; i < NCA; ++i)
      gload_lds16(A + aSrc[i] + k0, &lA[(wave + i * NW) * 512]);
#pragma unroll
    for (int i = 0; i < NCB; ++i)
      gload_lds16(Bw + bSrc[i] + k0, &lB[(wave + i * NW) * 512]);
    __syncthreads();
#pragma unroll
    for (int kk = 0; kk < BK; kk += 32) {
      bf16x8 af[FM], bfr[FN];
      const int lc = (kk >> 3) + (lane >> 4);   // logical 16B-chunk index 0..7
#pragma unroll
      for (int m2 = 0; m2 < FM; ++m2) {
        int row = wr * WROWS + m2 * 16 + (lane & 15);
        af[m2] = *(const bf16x8*)&lA[row * BK + ((lc ^ (row & 7)) << 3)];
      }
#pragma unroll
      for (int n2 = 0; n2 < FN; ++n2) {
        int row = wc * WCOLS + n2 * 16 + (lane & 15);
        bfr[n2] = *(const bf16x8*)&lB[row * BK + ((lc ^ (row & 7)) << 3)];
      }
#pragma unroll
      for (int m2 = 0; m2 < FM; ++m2)
#pragma unroll
        for (int n2 = 0; n2 < FN; ++n2)
          acc[m2][n2] = __builtin_amdgcn_mfma_f32_16x16x32_bf16(
              af[m2], bfr[n2], acc[m2][n2], 0, 0, 0);
    }
    __syncthreads();
  }

  const float* be = bias + (size_t)e * NN;
#pragma unroll
  for (int m2 = 0; m2 < FM; ++m2) {
    const int lr = wr * WROWS + m2 * 16 + (lane >> 4) * 4;
#pragma unroll
    for (int n2 = 0; n2 < FN; ++n2) {
      const int col = n0 + wc * WCOLS + n2 * 16 + (lane & 15);
      const float bv = be[col];
#pragma unroll
      for (int j = 0; j < 4; ++j) {
        const int arow = arow0 + lr + j;
        if (arow < ne_end) {
          float v = acc[m2][n2][j] + bv;
          if (MODE == 0) { v = fmaxf(v, 0.f); v = v * v; }
          Cout[(size_t)arow * NN + col] = f2bf(v);
        }
      }
    }
  }
}

// ---------------- combine: out[t] = g0*h2[p0] + g1*h2[p1] ----------------------
__global__ __launch_bounds__(256) void combine_kernel(
    const unsigned short* __restrict__ h2, const int* __restrict__ pos_list,
    const float* __restrict__ gates, float* __restrict__ out)
{
  const int wave = threadIdx.x >> 6, lane = threadIdx.x & 63;
  const int t = blockIdx.x * 4 + wave;
  const int p0 = pos_list[2 * t], p1 = pos_list[2 * t + 1];
  const float g0 = gates[2 * t], g1 = gates[2 * t + 1];
  const unsigned short* r0 = h2 + (size_t)p0 * HD;
  const unsigned short* r1 = h2 + (size_t)p1 * HD;
  float* o = out + (size_t)t * HD;
#pragma unroll
  for (int i = 0; i < 3; ++i) {
    int h = i * 256 + lane * 4;
    ushort4 a = *(const ushort4*)&r0[h];
    ushort4 b = *(const ushort4*)&r1[h];
    float4 o4;
    o4.x = g0 * bf2f(a.x) + g1 * bf2f(b.x);
    o4.y = g0 * bf2f(a.y) + g1 * bf2f(b.y);
    o4.z = g0 * bf2f(a.z) + g1 * bf2f(b.z);
    o4.w = g0 * bf2f(a.w) + g1 * bf2f(b.w);
    *(float4*)&o[h] = o4;
  }
}

// -------------------------------- launch ---------------------------------------
extern "C" void kernel_launch(void* const* d_in, const int* in_sizes, int n_in,
                              void* d_out, int out_size, void* d_ws, size_t ws_size,
                              hipStream_t stream)
{
  (void)in_sizes; (void)n_in; (void)ws_size; (void)out_size;
  const float* x  = (const float*)d_in[0];
  const float* rw = (const float*)d_in[1];
  const float* rb = (const float*)d_in[2];
  const float* w1 = (const float*)d_in[3];
  const float* b1 = (const float*)d_in[4];
  const float* w2 = (const float*)d_in[5];
  const float* b2 = (const float*)d_in[6];
  float* out = (float*)d_out;

  char* ws = (char*)d_ws;
  size_t off = 0;
  auto alloc = [&](size_t bytes) {
    off = (off + 255) & ~(size_t)255;
    void* p = ws + off;
    off += bytes;
    return p;
  };
  unsigned short* xb  = (unsigned short*)alloc((size_t)TOK * HD * 2);
  unsigned short* w1t = (unsigned short*)alloc((size_t)E_EXP * FD * HD * 2);
  unsigned short* w2t = (unsigned short*)alloc((size_t)E_EXP * HD * FD * 2);
  unsigned short* h1  = (unsigned short*)alloc((size_t)CAP * FD * 2);
  unsigned short* h2  = (unsigned short*)alloc((size_t)CAP * HD * 2);
  int*   token_list = (int*)alloc(CAP * 4);
  int*   pos_list   = (int*)alloc((size_t)TOK * 2 * 4);
  int*   ids        = (int*)alloc((size_t)TOK * 2 * 4);
  float* gates      = (float*)alloc((size_t)TOK * 2 * 4);
  float* probs      = (float*)alloc((size_t)TOK * 8 * 4);
  int*   meta       = (int*)alloc(1024 * 4);
  char*  ctrl       = (char*)token_list;
  size_t ctrl_bytes = (ws + off) - ctrl;

  hipMemsetAsync(ctrl, 0, ctrl_bytes, stream);

  router_kernel<<<TOK / 4, 256, 0, stream>>>(x, rw, rb, xb, probs, ids, gates);
  transpose_kernel<<<dim3(FD / 32, HD / 32, E_EXP), 256, 0, stream>>>(w1, w1t, HD, FD);
  transpose_kernel<<<dim3(HD / 32, FD / 32, E_EXP), 256, 0, stream>>>(w2, w2t, FD, HD);
  stats_kernel<<<1, 256, 0, stream>>>(ids, probs, meta, out + (size_t)TOK * HD);
  scatter_kernel<<<TOK / 256, 256, 0, stream>>>(ids, meta, token_list, pos_list);
  // GEMM1: 71 max m-tiles x 12 n-tiles, 8-wave blocks (64x64 per wave)
  moe_gemm<128, 256, 0, 8><<<71 * (FD / 256), 512, 0, stream>>>(
      xb, w1t, b1, token_list, meta, h1, HD, FD);
  // GEMM2: 135 max m-tiles x 3 n-tiles, 4-wave blocks (32x128 per wave)
  moe_gemm<64, 256, 1, 4><<<135 * (HD / 256), 256, 0, stream>>>(
      h1, w2t, b2, token_list, meta, h2, FD, HD);
  combine_kernel<<<TOK / 4, 256, 0, stream>>>(h2, pos_list, gates, out);
}

// Round 6
// 210.202 us; speedup vs baseline: 1.3657x; 1.0110x over previous
//
#include <hip/hip_runtime.h>
#include <hip/hip_bf16.h>
#include <stdint.h>

#define E_EXP 8
#define TOK   4096
#define HD    768
#define FD    3072
#define BK    64
#define CAP   8320   // 8192 assignments + max per-expert tile padding

typedef __attribute__((ext_vector_type(8))) short bf16x8;
typedef __attribute__((ext_vector_type(4))) float f32x4;

__device__ __forceinline__ unsigned short f2bf(float f) {
  union { float f; unsigned u; } v; v.f = f;
  unsigned r = v.u + 0x7fffu + ((v.u >> 16) & 1u);
  return (unsigned short)(r >> 16);
}
__device__ __forceinline__ float bf2f(unsigned short u) {
  union { unsigned u; float f; } v; v.u = ((unsigned)u) << 16;
  return v.f;
}

__device__ __forceinline__ void gload_lds16(const void* g, void* l) {
  __builtin_amdgcn_global_load_lds(
      (const __attribute__((address_space(1))) unsigned int*)g,
      (__attribute__((address_space(3))) unsigned int*)l, 16, 0, 0);
}

// bijective XCD-chunking swizzle (m204): orig%8 = XCD, give each XCD a
// contiguous wgid range so neighboring tiles share L2.
__device__ __forceinline__ int xcd_swizzle(int orig, int nwg) {
  int xcd = orig & 7, base = orig >> 3;
  int q = nwg >> 3, r = nwg & 7;
  return (xcd < r ? xcd * (q + 1) : r * (q + 1) + (xcd - r) * q) + base;
}

// ---------------- router: scores, softmax, top-2, x->bf16; NO atomics ----------
__global__ __launch_bounds__(256) void router_kernel(
    const float* __restrict__ x, const float* __restrict__ rw,
    const float* __restrict__ rb, unsigned short* __restrict__ xb,
    float* __restrict__ probs, int* __restrict__ ids,
    float* __restrict__ gates)
{
  __shared__ float lrw[E_EXP * HD];   // [e][h]
  for (int i = threadIdx.x; i < E_EXP * HD; i += 256) {
    int h = i >> 3, e = i & 7;
    lrw[e * HD + h] = rw[i];
  }
  __syncthreads();
  const int wave = threadIdx.x >> 6, lane = threadIdx.x & 63;
  const int t = blockIdx.x * 4 + wave;
  const float* xrow = x + (size_t)t * HD;
  float acc[8] = {0, 0, 0, 0, 0, 0, 0, 0};
#pragma unroll
  for (int i = 0; i < HD / 64; ++i) {
    int h = i * 64 + lane;
    float xv = xrow[h];
    xb[(size_t)t * HD + h] = f2bf(xv);
#pragma unroll
    for (int e = 0; e < 8; ++e) acc[e] += xv * lrw[e * HD + h];
  }
#pragma unroll
  for (int d = 1; d < 64; d <<= 1) {
#pragma unroll
    for (int e = 0; e < 8; ++e) acc[e] += __shfl_xor(acc[e], d);
  }
  if (lane == 0) {
    float p[8]; float m = -1e30f, sum = 0.f;
#pragma unroll
    for (int e = 0; e < 8; ++e) { p[e] = acc[e] + rb[e]; m = fmaxf(m, p[e]); }
#pragma unroll
    for (int e = 0; e < 8; ++e) { p[e] = __expf(p[e] - m); sum += p[e]; }
    float inv = 1.f / sum;
#pragma unroll
    for (int e = 0; e < 8; ++e) p[e] *= inv;
    int i1 = 0;
#pragma unroll
    for (int e = 1; e < 8; ++e) if (p[e] > p[i1]) i1 = e;   // ties -> lower idx
    int i2 = (i1 == 0) ? 1 : 0;
#pragma unroll
    for (int e = 0; e < 8; ++e) if (e != i1 && p[e] > p[i2]) i2 = e;
    ids[t * 2] = i1; ids[t * 2 + 1] = i2;
    float den = 1.f / (p[i1] + p[i2] + 1e-9f);
    gates[t * 2] = p[i1] * den; gates[t * 2 + 1] = p[i2] * den;
#pragma unroll
    for (int e = 0; e < 8; ++e) probs[t * 8 + e] = p[e];
  }
}

// ---------------- weight transpose: W[e][Kd][Nd] f32 -> Wt[e][Nd][Kd] bf16 ------
__global__ __launch_bounds__(256) void transpose_kernel(
    const float* __restrict__ W, unsigned short* __restrict__ Wt,
    int Kd, int Nd)
{
  __shared__ float tile[32][33];
  const int e = blockIdx.z;
  const int n0 = blockIdx.x * 32, k0 = blockIdx.y * 32;
  const int ci = threadIdx.x & 31, ri = threadIdx.x >> 5;
  const float* src = W + ((size_t)e * Kd + k0) * Nd + n0;
#pragma unroll
  for (int i = 0; i < 32; i += 8)
    tile[ri + i][ci] = src[(size_t)(ri + i) * Nd + ci];
  __syncthreads();
  unsigned short* dst = Wt + ((size_t)e * Nd + n0) * Kd + k0;
  const int co = (threadIdx.x & 15) * 2, ro = threadIdx.x >> 4;
#pragma unroll
  for (int i = 0; i < 32; i += 16) {
    int r = ro + i;
    unsigned v = (unsigned)f2bf(tile[co][r]) | ((unsigned)f2bf(tile[co + 1][r]) << 16);
    *(unsigned*)&dst[(size_t)r * Kd + co] = v;
  }
}

// ---------------- stats: counts, probs_sum, bases, tile maps, bal loss ----------
__global__ __launch_bounds__(256) void stats_kernel(
    const int* __restrict__ ids, const float* __restrict__ probs,
    int* __restrict__ meta, float* __restrict__ loss_out)
{
  __shared__ int cnt[8], top1c[8];
  __shared__ float wsum[4][8];
  if (threadIdx.x < 8) { cnt[threadIdx.x] = 0; top1c[threadIdx.x] = 0; }
  __syncthreads();
  float local[8] = {0, 0, 0, 0, 0, 0, 0, 0};
  for (int t = threadIdx.x; t < TOK; t += 256) {
    int e0 = ids[2 * t], e1 = ids[2 * t + 1];
    atomicAdd(&cnt[e0], 1); atomicAdd(&cnt[e1], 1); atomicAdd(&top1c[e0], 1);
    const float4* pr = (const float4*)&probs[(size_t)t * 8];
    float4 a = pr[0], b = pr[1];
    local[0] += a.x; local[1] += a.y; local[2] += a.z; local[3] += a.w;
    local[4] += b.x; local[5] += b.y; local[6] += b.z; local[7] += b.w;
  }
#pragma unroll
  for (int d = 1; d < 64; d <<= 1) {
#pragma unroll
    for (int e = 0; e < 8; ++e) local[e] += __shfl_xor(local[e], d);
  }
  const int wave = threadIdx.x >> 6, lane = threadIdx.x & 63;
  if (lane == 0) {
#pragma unroll
    for (int e = 0; e < 8; ++e) wsum[wave][e] = local[e];
  }
  __syncthreads();
  if (threadIdx.x == 0) {
    int total = 0, nt1 = 0, nt2 = 0;
    for (int e = 0; e < 8; ++e) {
      int c = cnt[e];
      meta[e] = c;
      meta[16 + e] = total;                     // base
      int t1 = (c + 127) >> 7;
      for (int i = 0; i < t1; ++i) { meta[64 + nt1 * 2] = e; meta[64 + nt1 * 2 + 1] = total + i * 128; ++nt1; }
      int t2 = (c + 63) >> 6;
      for (int i = 0; i < t2; ++i) { meta[256 + nt2 * 2] = e; meta[256 + nt2 * 2 + 1] = total + i * 64; ++nt2; }
      total += c;
    }
    meta[32] = nt1; meta[33] = nt2;
    float loss = 0.f;
    for (int e = 0; e < 8; ++e) {
      float psum = wsum[0][e] + wsum[1][e] + wsum[2][e] + wsum[3][e];
      loss += ((float)top1c[e] / 4096.f) * (psum / 4096.f);
    }
    loss_out[0] = 0.001f * loss;
  }
}

// ---------------- scatter: block-aggregated; records pos for combine -----------
__global__ __launch_bounds__(256) void scatter_kernel(
    const int* __restrict__ ids, int* __restrict__ meta,
    int* __restrict__ token_list, int* __restrict__ pos_list)
{
  __shared__ int lcnt[8];
  __shared__ int lbase[8];
  if (threadIdx.x < 8) lcnt[threadIdx.x] = 0;
  __syncthreads();
  const int t = blockIdx.x * 256 + threadIdx.x;
  const int e0 = ids[t * 2], e1 = ids[t * 2 + 1];
  const int s0 = atomicAdd(&lcnt[e0], 1);
  const int s1 = atomicAdd(&lcnt[e1], 1);
  __syncthreads();
  if (threadIdx.x < 8)
    lbase[threadIdx.x] = atomicAdd(&meta[24 + threadIdx.x], lcnt[threadIdx.x]);
  __syncthreads();
  int p0 = meta[16 + e0] + lbase[e0] + s0;
  int p1 = meta[16 + e1] + lbase[e1] + s1;
  token_list[p0] = t; pos_list[t * 2] = p0;
  token_list[p1] = t; pos_list[t * 2 + 1] = p1;
}

// ---------------- grouped GEMM (MODE 0: x@w1 + relu^2 -> h1 bf16;
//                  MODE 1: h1@w2 + b2 -> h2 bf16 rows) -------------------------
// NW waves per block (NW*64 threads). Wave grid: 2 x (NW/2); per-wave output
// (BM/2) x (BN/(NW/2)). 1-D grid, n-fastest + bijective XCD chunking.
// LDS: linear rows of BK=64 bf16; 16B k-chunks XOR-swizzled by (row&7) on BOTH
// the global source address (staging) and the ds_read address (rule 21).
template<int BM, int BN, int MODE, int NW>
__global__ __launch_bounds__(NW * 64, 4) void moe_gemm(
    const unsigned short* __restrict__ A,
    const unsigned short* __restrict__ Bw,   // [E][NN][Kdim] bf16 (pre-transposed)
    const float* __restrict__ bias,          // [E][NN]
    const int* __restrict__ token_list,
    const int* __restrict__ meta,
    unsigned short* __restrict__ Cout,       // MODE0: h1[CAP][FD]; MODE1: h2[CAP][HD]
    const int Kdim, const int NN)
{
  const int NY = NN / BN;
  const int wgid = xcd_swizzle(blockIdx.x, gridDim.x);
  const int mt = wgid / NY;
  const int ny = wgid - mt * NY;
  const int nt_total = meta[32 + MODE];
  if (mt >= nt_total) return;
  const int* tmap = meta + (MODE == 0 ? 64 : 256);
  const int e = tmap[mt * 2], arow0 = tmap[mt * 2 + 1];
  const int ne_end = meta[16 + e] + meta[e];
  const int n0 = ny * BN;

  __shared__ unsigned short lA[BM * BK];
  __shared__ unsigned short lB[BN * BK];

  const int tid = threadIdx.x;
  const int wave = tid >> 6, lane = tid & 63;
  constexpr int WC_N = NW / 2;              // waves along N
  const int wr = wave / WC_N, wc = wave % WC_N;
  constexpr int WROWS = BM / 2;             // per-wave rows
  constexpr int WCOLS = BN / WC_N;          // per-wave cols
  constexpr int FM = WROWS / 16, FN = WCOLS / 16;
  constexpr int NCA = (BM / 8) / NW;        // A 1KB-chunks per wave
  constexpr int NCB = (BN / 8) / NW;        // B chunks per wave

  // swizzled k-offset for staging: logical chunk (lane&7) XOR row-in-8 (lane>>3)&7
  const int kswz = ((lane & 7) ^ ((lane >> 3) & 7)) * 8;

  size_t aSrc[NCA];
#pragma unroll
  for (int i = 0; i < NCA; ++i) {
    int c = wave + i * NW;
    int r = c * 8 + (lane >> 3);
    int grow = (MODE == 0) ? token_list[arow0 + r] : (arow0 + r);
    aSrc[i] = (size_t)grow * Kdim + kswz;
  }
  size_t bSrc[NCB];
#pragma unroll
  for (int i = 0; i < NCB; ++i) {
    int c = wave + i * NW;
    int n = n0 + c * 8 + (lane >> 3);
    bSrc[i] = ((size_t)e * NN + n) * Kdim + kswz;
  }

  f32x4 acc[FM][FN] = {};

  for (int k0 = 0; k0 < Kdim; k0 += BK) {
#pragma unroll
    for (int i = 0; i < NCA; ++i)
      gload_lds16(A + aSrc[i] + k0, &lA[(wave + i * NW) * 512]);
#pragma unroll
    for (int i = 0; i < NCB; ++i)
      gload_lds16(Bw + bSrc[i] + k0, &lB[(wave + i * NW) * 512]);
    __syncthreads();
#pragma unroll
    for (int kk = 0; kk < BK; kk += 32) {
      bf16x8 af[FM], bfr[FN];
      const int lc = (kk >> 3) + (lane >> 4);   // logical 16B-chunk index 0..7
#pragma unroll
      for (int m2 = 0; m2 < FM; ++m2) {
        int row = wr * WROWS + m2 * 16 + (lane & 15);
        af[m2] = *(const bf16x8*)&lA[row * BK + ((lc ^ (row & 7)) << 3)];
      }
#pragma unroll
      for (int n2 = 0; n2 < FN; ++n2) {
        int row = wc * WCOLS + n2 * 16 + (lane & 15);
        bfr[n2] = *(const bf16x8*)&lB[row * BK + ((lc ^ (row & 7)) << 3)];
      }
#pragma unroll
      for (int m2 = 0; m2 < FM; ++m2)
#pragma unroll
        for (int n2 = 0; n2 < FN; ++n2)
          acc[m2][n2] = __builtin_amdgcn_mfma_f32_16x16x32_bf16(
              af[m2], bfr[n2], acc[m2][n2], 0, 0, 0);
    }
    __syncthreads();
  }

  const float* be = bias + (size_t)e * NN;
#pragma unroll
  for (int m2 = 0; m2 < FM; ++m2) {
    const int lr = wr * WROWS + m2 * 16 + (lane >> 4) * 4;
#pragma unroll
    for (int n2 = 0; n2 < FN; ++n2) {
      const int col = n0 + wc * WCOLS + n2 * 16 + (lane & 15);
      const float bv = be[col];
#pragma unroll
      for (int j = 0; j < 4; ++j) {
        const int arow = arow0 + lr + j;
        if (arow < ne_end) {
          float v = acc[m2][n2][j] + bv;
          if (MODE == 0) { v = fmaxf(v, 0.f); v = v * v; }
          Cout[(size_t)arow * NN + col] = f2bf(v);
        }
      }
    }
  }
}

// ---------------- combine: out[t] = g0*h2[p0] + g1*h2[p1] ----------------------
__global__ __launch_bounds__(256) void combine_kernel(
    const unsigned short* __restrict__ h2, const int* __restrict__ pos_list,
    const float* __restrict__ gates, float* __restrict__ out)
{
  const int wave = threadIdx.x >> 6, lane = threadIdx.x & 63;
  const int t = blockIdx.x * 4 + wave;
  const int p0 = pos_list[2 * t], p1 = pos_list[2 * t + 1];
  const float g0 = gates[2 * t], g1 = gates[2 * t + 1];
  const unsigned short* r0 = h2 + (size_t)p0 * HD;
  const unsigned short* r1 = h2 + (size_t)p1 * HD;
  float* o = out + (size_t)t * HD;
#pragma unroll
  for (int i = 0; i < 3; ++i) {
    int h = i * 256 + lane * 4;
    ushort4 a = *(const ushort4*)&r0[h];
    ushort4 b = *(const ushort4*)&r1[h];
    float4 o4;
    o4.x = g0 * bf2f(a.x) + g1 * bf2f(b.x);
    o4.y = g0 * bf2f(a.y) + g1 * bf2f(b.y);
    o4.z = g0 * bf2f(a.z) + g1 * bf2f(b.z);
    o4.w = g0 * bf2f(a.w) + g1 * bf2f(b.w);
    *(float4*)&o[h] = o4;
  }
}

// -------------------------------- launch ---------------------------------------
extern "C" void kernel_launch(void* const* d_in, const int* in_sizes, int n_in,
                              void* d_out, int out_size, void* d_ws, size_t ws_size,
                              hipStream_t stream)
{
  (void)in_sizes; (void)n_in; (void)ws_size; (void)out_size;
  const float* x  = (const float*)d_in[0];
  const float* rw = (const float*)d_in[1];
  const float* rb = (const float*)d_in[2];
  const float* w1 = (const float*)d_in[3];
  const float* b1 = (const float*)d_in[4];
  const float* w2 = (const float*)d_in[5];
  const float* b2 = (const float*)d_in[6];
  float* out = (float*)d_out;

  char* ws = (char*)d_ws;
  size_t off = 0;
  auto alloc = [&](size_t bytes) {
    off = (off + 255) & ~(size_t)255;
    void* p = ws + off;
    off += bytes;
    return p;
  };
  unsigned short* xb  = (unsigned short*)alloc((size_t)TOK * HD * 2);
  unsigned short* w1t = (unsigned short*)alloc((size_t)E_EXP * FD * HD * 2);
  unsigned short* w2t = (unsigned short*)alloc((size_t)E_EXP * HD * FD * 2);
  unsigned short* h1  = (unsigned short*)alloc((size_t)CAP * FD * 2);
  unsigned short* h2  = (unsigned short*)alloc((size_t)CAP * HD * 2);
  int*   token_list = (int*)alloc(CAP * 4);
  int*   pos_list   = (int*)alloc((size_t)TOK * 2 * 4);
  int*   ids        = (int*)alloc((size_t)TOK * 2 * 4);
  float* gates      = (float*)alloc((size_t)TOK * 2 * 4);
  float* probs      = (float*)alloc((size_t)TOK * 8 * 4);
  int*   meta       = (int*)alloc(1024 * 4);
  char*  ctrl       = (char*)token_list;
  size_t ctrl_bytes = (ws + off) - ctrl;

  hipMemsetAsync(ctrl, 0, ctrl_bytes, stream);

  router_kernel<<<TOK / 4, 256, 0, stream>>>(x, rw, rb, xb, probs, ids, gates);
  transpose_kernel<<<dim3(FD / 32, HD / 32, E_EXP), 256, 0, stream>>>(w1, w1t, HD, FD);
  transpose_kernel<<<dim3(HD / 32, FD / 32, E_EXP), 256, 0, stream>>>(w2, w2t, FD, HD);
  stats_kernel<<<1, 256, 0, stream>>>(ids, probs, meta, out + (size_t)TOK * HD);
  scatter_kernel<<<TOK / 256, 256, 0, stream>>>(ids, meta, token_list, pos_list);
  // GEMM1: 71 max m-tiles x 24 n-tiles, 4-wave blocks (64x64 per wave, m97 shape)
  moe_gemm<128, 128, 0, 4><<<71 * (FD / 128), 256, 0, stream>>>(
      xb, w1t, b1, token_list, meta, h1, HD, FD);
  // GEMM2: 135 max m-tiles x 6 n-tiles, 4-wave blocks (32x64 per wave)
  moe_gemm<64, 128, 1, 4><<<135 * (HD / 128), 256, 0, stream>>>(
      h1, w2t, b2, token_list, meta, h2, FD, HD);
  combine_kernel<<<TOK / 4, 256, 0, stream>>>(h2, pos_list, gates, out);
}

// Round 7
// 201.796 us; speedup vs baseline: 1.4225x; 1.0417x over previous
//
#include <hip/hip_runtime.h>
#include <hip/hip_bf16.h>
#include <stdint.h>

#define E_EXP 8
#define TOK   4096
#define HD    768
#define FD    3072
#define BK    64
#define CAP   8320   // 8192 assignments + max per-expert tile padding

typedef __attribute__((ext_vector_type(8))) short bf16x8;
typedef __attribute__((ext_vector_type(4))) float f32x4;

__device__ __forceinline__ unsigned short f2bf(float f) {
  union { float f; unsigned u; } v; v.f = f;
  unsigned r = v.u + 0x7fffu + ((v.u >> 16) & 1u);
  return (unsigned short)(r >> 16);
}
__device__ __forceinline__ float bf2f(unsigned short u) {
  union { unsigned u; float f; } v; v.u = ((unsigned)u) << 16;
  return v.f;
}

__device__ __forceinline__ void gload_lds16(const void* g, void* l) {
  __builtin_amdgcn_global_load_lds(
      (const __attribute__((address_space(1))) unsigned int*)g,
      (__attribute__((address_space(3))) unsigned int*)l, 16, 0, 0);
}

// bijective XCD-chunking swizzle (m204)
__device__ __forceinline__ int xcd_swizzle(int orig, int nwg) {
  int xcd = orig & 7, base = orig >> 3;
  int q = nwg >> 3, r = nwg & 7;
  return (xcd < r ? xcd * (q + 1) : r * (q + 1) + (xcd - r) * q) + base;
}

// ---------------- router: scores, softmax, top-2, x->bf16; NO atomics ----------
__global__ __launch_bounds__(256) void router_kernel(
    const float* __restrict__ x, const float* __restrict__ rw,
    const float* __restrict__ rb, unsigned short* __restrict__ xb,
    float* __restrict__ probs, int* __restrict__ ids,
    float* __restrict__ gates)
{
  __shared__ float lrw[E_EXP * HD];   // [e][h]
  for (int i = threadIdx.x; i < E_EXP * HD; i += 256) {
    int h = i >> 3, e = i & 7;
    lrw[e * HD + h] = rw[i];
  }
  __syncthreads();
  const int wave = threadIdx.x >> 6, lane = threadIdx.x & 63;
  const int t = blockIdx.x * 4 + wave;
  const float* xrow = x + (size_t)t * HD;
  float acc[8] = {0, 0, 0, 0, 0, 0, 0, 0};
#pragma unroll
  for (int i = 0; i < HD / 64; ++i) {
    int h = i * 64 + lane;
    float xv = xrow[h];
    xb[(size_t)t * HD + h] = f2bf(xv);
#pragma unroll
    for (int e = 0; e < 8; ++e) acc[e] += xv * lrw[e * HD + h];
  }
#pragma unroll
  for (int d = 1; d < 64; d <<= 1) {
#pragma unroll
    for (int e = 0; e < 8; ++e) acc[e] += __shfl_xor(acc[e], d);
  }
  if (lane == 0) {
    float p[8]; float m = -1e30f, sum = 0.f;
#pragma unroll
    for (int e = 0; e < 8; ++e) { p[e] = acc[e] + rb[e]; m = fmaxf(m, p[e]); }
#pragma unroll
    for (int e = 0; e < 8; ++e) { p[e] = __expf(p[e] - m); sum += p[e]; }
    float inv = 1.f / sum;
#pragma unroll
    for (int e = 0; e < 8; ++e) p[e] *= inv;
    int i1 = 0;
#pragma unroll
    for (int e = 1; e < 8; ++e) if (p[e] > p[i1]) i1 = e;   // ties -> lower idx
    int i2 = (i1 == 0) ? 1 : 0;
#pragma unroll
    for (int e = 0; e < 8; ++e) if (e != i1 && p[e] > p[i2]) i2 = e;
    ids[t * 2] = i1; ids[t * 2 + 1] = i2;
    float den = 1.f / (p[i1] + p[i2] + 1e-9f);
    gates[t * 2] = p[i1] * den; gates[t * 2 + 1] = p[i2] * den;
#pragma unroll
    for (int e = 0; e < 8; ++e) probs[t * 8 + e] = p[e];
  }
}

// ---------------- merged weight transpose: w1 and w2 in one launch -------------
// W[e][Kd][Nd] f32 -> Wt[e][Nd][Kd] bf16
#define W1_TILES (E_EXP * (FD / 32) * (HD / 32))   // 18432
#define W2_TILES (E_EXP * (HD / 32) * (FD / 32))   // 18432
__global__ __launch_bounds__(256) void transpose_kernel(
    const float* __restrict__ w1, unsigned short* __restrict__ w1t,
    const float* __restrict__ w2, unsigned short* __restrict__ w2t)
{
  __shared__ float tile[32][33];
  int id = blockIdx.x;
  const float* W; unsigned short* Wt; int Kd, Nd;
  if (id < W1_TILES) {
    W = w1; Wt = w1t; Kd = HD; Nd = FD;
  } else {
    id -= W1_TILES; W = w2; Wt = w2t; Kd = FD; Nd = HD;
  }
  const int nx = Nd / 32;
  const int e = id / (nx * (Kd / 32));
  const int rem = id % (nx * (Kd / 32));
  const int n0 = (rem % nx) * 32, k0 = (rem / nx) * 32;

  const int ci = threadIdx.x & 31, ri = threadIdx.x >> 5;
  const float* src = W + ((size_t)e * Kd + k0) * Nd + n0;
#pragma unroll
  for (int i = 0; i < 32; i += 8)
    tile[ri + i][ci] = src[(size_t)(ri + i) * Nd + ci];
  __syncthreads();
  unsigned short* dst = Wt + ((size_t)e * Nd + n0) * Kd + k0;
  const int co = (threadIdx.x & 15) * 2, ro = threadIdx.x >> 4;
#pragma unroll
  for (int i = 0; i < 32; i += 16) {
    int r = ro + i;
    unsigned v = (unsigned)f2bf(tile[co][r]) | ((unsigned)f2bf(tile[co + 1][r]) << 16);
    *(unsigned*)&dst[(size_t)r * Kd + co] = v;
  }
}

// ---------------- stats: counts, probs_sum, bases, tile map (BM=128), loss ------
__global__ __launch_bounds__(256) void stats_kernel(
    const int* __restrict__ ids, const float* __restrict__ probs,
    int* __restrict__ meta, float* __restrict__ loss_out)
{
  __shared__ int cnt[8], top1c[8];
  __shared__ float wsum[4][8];
  if (threadIdx.x < 8) { cnt[threadIdx.x] = 0; top1c[threadIdx.x] = 0; }
  __syncthreads();
  float local[8] = {0, 0, 0, 0, 0, 0, 0, 0};
  for (int t = threadIdx.x; t < TOK; t += 256) {
    int e0 = ids[2 * t], e1 = ids[2 * t + 1];
    atomicAdd(&cnt[e0], 1); atomicAdd(&cnt[e1], 1); atomicAdd(&top1c[e0], 1);
    const float4* pr = (const float4*)&probs[(size_t)t * 8];
    float4 a = pr[0], b = pr[1];
    local[0] += a.x; local[1] += a.y; local[2] += a.z; local[3] += a.w;
    local[4] += b.x; local[5] += b.y; local[6] += b.z; local[7] += b.w;
  }
#pragma unroll
  for (int d = 1; d < 64; d <<= 1) {
#pragma unroll
    for (int e = 0; e < 8; ++e) local[e] += __shfl_xor(local[e], d);
  }
  const int wave = threadIdx.x >> 6, lane = threadIdx.x & 63;
  if (lane == 0) {
#pragma unroll
    for (int e = 0; e < 8; ++e) wsum[wave][e] = local[e];
  }
  __syncthreads();
  if (threadIdx.x == 0) {
    int total = 0, nt1 = 0;
    for (int e = 0; e < 8; ++e) {
      int c = cnt[e];
      meta[e] = c;
      meta[16 + e] = total;                     // base
      int t1 = (c + 127) >> 7;
      for (int i = 0; i < t1; ++i) { meta[64 + nt1 * 2] = e; meta[64 + nt1 * 2 + 1] = total + i * 128; ++nt1; }
      total += c;
    }
    meta[32] = nt1;
    float loss = 0.f;
    for (int e = 0; e < 8; ++e) {
      float psum = wsum[0][e] + wsum[1][e] + wsum[2][e] + wsum[3][e];
      loss += ((float)top1c[e] / 4096.f) * (psum / 4096.f);
    }
    loss_out[0] = 0.001f * loss;
  }
}

// ---------------- scatter: block-aggregated; records pos for combine -----------
__global__ __launch_bounds__(256) void scatter_kernel(
    const int* __restrict__ ids, int* __restrict__ meta,
    int* __restrict__ token_list, int* __restrict__ pos_list)
{
  __shared__ int lcnt[8];
  __shared__ int lbase[8];
  if (threadIdx.x < 8) lcnt[threadIdx.x] = 0;
  __syncthreads();
  const int t = blockIdx.x * 256 + threadIdx.x;
  const int e0 = ids[t * 2], e1 = ids[t * 2 + 1];
  const int s0 = atomicAdd(&lcnt[e0], 1);
  const int s1 = atomicAdd(&lcnt[e1], 1);
  __syncthreads();
  if (threadIdx.x < 8)
    lbase[threadIdx.x] = atomicAdd(&meta[24 + threadIdx.x], lcnt[threadIdx.x]);
  __syncthreads();
  int p0 = meta[16 + e0] + lbase[e0] + s0;
  int p1 = meta[16 + e1] + lbase[e1] + s1;
  token_list[p0] = t; pos_list[t * 2] = p0;
  token_list[p1] = t; pos_list[t * 2 + 1] = p1;
}

// ---------------- grouped GEMM (MODE 0: x@w1 + relu^2 -> h1 bf16;
//                  MODE 1: h1@w2 (+b2 in kp0) -> h2 partial bf16 rows) ----------
// NW waves (NW*64 thr), per-wave (BM/2) x (BN/(NW/2)). 1-D grid, decode
// wgid -> (mt, ny, kp) n/k-fastest + bijective XCD chunking. NKP = split-K ways;
// partial kp writes Cout + kp*CAP*NN; bias only in kp==0.
// LDS: linear rows of BK=64 bf16; 16B k-chunks XOR-swizzled by (row&7) on BOTH
// the global source address (staging) and the ds_read address (rule 21).
template<int BM, int BN, int MODE, int NW, int NKP>
__global__ __launch_bounds__(NW * 64, 4) void moe_gemm(
    const unsigned short* __restrict__ A,
    const unsigned short* __restrict__ Bw,   // [E][NN][Kdim] bf16 (pre-transposed)
    const float* __restrict__ bias,          // [E][NN]
    const int* __restrict__ token_list,
    const int* __restrict__ meta,
    unsigned short* __restrict__ Cout,
    const int Kdim, const int NN)
{
  const int NY = NN / BN;
  const int wgid = xcd_swizzle(blockIdx.x, gridDim.x);
  const int mt = wgid / (NY * NKP);
  const int slot = wgid - mt * (NY * NKP);
  const int ny = slot % NY;
  const int kp = slot / NY;
  const int nt_total = meta[32];
  if (mt >= nt_total) return;
  const int* tmap = meta + 64;
  const int e = tmap[mt * 2], arow0 = tmap[mt * 2 + 1];
  const int ne_end = meta[16 + e] + meta[e];
  const int n0 = ny * BN;
  const int KLEN = Kdim / NKP;
  const int kbeg = kp * KLEN;
  unsigned short* Cp = Cout + (size_t)kp * CAP * NN;

  __shared__ unsigned short lA[BM * BK];
  __shared__ unsigned short lB[BN * BK];

  const int tid = threadIdx.x;
  const int wave = tid >> 6, lane = tid & 63;
  constexpr int WC_N = NW / 2;              // waves along N
  const int wr = wave / WC_N, wc = wave % WC_N;
  constexpr int WROWS = BM / 2;             // per-wave rows
  constexpr int WCOLS = BN / WC_N;          // per-wave cols
  constexpr int FM = WROWS / 16, FN = WCOLS / 16;
  constexpr int NCA = (BM / 8) / NW;        // A 1KB-chunks per wave
  constexpr int NCB = (BN / 8) / NW;        // B chunks per wave

  // swizzled k-offset for staging: logical chunk (lane&7) XOR row-in-8 (lane>>3)&7
  const int kswz = ((lane & 7) ^ ((lane >> 3) & 7)) * 8;

  size_t aSrc[NCA];
#pragma unroll
  for (int i = 0; i < NCA; ++i) {
    int c = wave + i * NW;
    int r = c * 8 + (lane >> 3);
    int grow = (MODE == 0) ? token_list[arow0 + r] : (arow0 + r);
    aSrc[i] = (size_t)grow * Kdim + kbeg + kswz;
  }
  size_t bSrc[NCB];
#pragma unroll
  for (int i = 0; i < NCB; ++i) {
    int c = wave + i * NW;
    int n = n0 + c * 8 + (lane >> 3);
    bSrc[i] = ((size_t)e * NN + n) * Kdim + kbeg + kswz;
  }

  f32x4 acc[FM][FN] = {};

  for (int k0 = 0; k0 < KLEN; k0 += BK) {
#pragma unroll
    for (int i = 0; i < NCA; ++i)
      gload_lds16(A + aSrc[i] + k0, &lA[(wave + i * NW) * 512]);
#pragma unroll
    for (int i = 0; i < NCB; ++i)
      gload_lds16(Bw + bSrc[i] + k0, &lB[(wave + i * NW) * 512]);
    __syncthreads();
#pragma unroll
    for (int kk = 0; kk < BK; kk += 32) {
      bf16x8 af[FM], bfr[FN];
      const int lc = (kk >> 3) + (lane >> 4);   // logical 16B-chunk index 0..7
#pragma unroll
      for (int m2 = 0; m2 < FM; ++m2) {
        int row = wr * WROWS + m2 * 16 + (lane & 15);
        af[m2] = *(const bf16x8*)&lA[row * BK + ((lc ^ (row & 7)) << 3)];
      }
#pragma unroll
      for (int n2 = 0; n2 < FN; ++n2) {
        int row = wc * WCOLS + n2 * 16 + (lane & 15);
        bfr[n2] = *(const bf16x8*)&lB[row * BK + ((lc ^ (row & 7)) << 3)];
      }
#pragma unroll
      for (int m2 = 0; m2 < FM; ++m2)
#pragma unroll
        for (int n2 = 0; n2 < FN; ++n2)
          acc[m2][n2] = __builtin_amdgcn_mfma_f32_16x16x32_bf16(
              af[m2], bfr[n2], acc[m2][n2], 0, 0, 0);
    }
    __syncthreads();
  }

  const float* be = bias + (size_t)e * NN;
#pragma unroll
  for (int m2 = 0; m2 < FM; ++m2) {
    const int lr = wr * WROWS + m2 * 16 + (lane >> 4) * 4;
#pragma unroll
    for (int n2 = 0; n2 < FN; ++n2) {
      const int col = n0 + wc * WCOLS + n2 * 16 + (lane & 15);
      const float bv = (kp == 0) ? be[col] : 0.f;
#pragma unroll
      for (int j = 0; j < 4; ++j) {
        const int arow = arow0 + lr + j;
        if (arow < ne_end) {
          float v = acc[m2][n2][j] + bv;
          if (MODE == 0) { v = fmaxf(v, 0.f); v = v * v; }
          Cp[(size_t)arow * NN + col] = f2bf(v);
        }
      }
    }
  }
}

// ---------------- combine: out[t] = g0*(h2a+h2b)[p0] + g1*(h2a+h2b)[p1] --------
__global__ __launch_bounds__(256) void combine_kernel(
    const unsigned short* __restrict__ h2, const int* __restrict__ pos_list,
    const float* __restrict__ gates, float* __restrict__ out)
{
  const unsigned short* h2b = h2 + (size_t)CAP * HD;
  const int wave = threadIdx.x >> 6, lane = threadIdx.x & 63;
  const int t = blockIdx.x * 4 + wave;
  const int p0 = pos_list[2 * t], p1 = pos_list[2 * t + 1];
  const float g0 = gates[2 * t], g1 = gates[2 * t + 1];
  const unsigned short* r0a = h2  + (size_t)p0 * HD;
  const unsigned short* r0b = h2b + (size_t)p0 * HD;
  const unsigned short* r1a = h2  + (size_t)p1 * HD;
  const unsigned short* r1b = h2b + (size_t)p1 * HD;
  float* o = out + (size_t)t * HD;
#pragma unroll
  for (int i = 0; i < 3; ++i) {
    int h = i * 256 + lane * 4;
    ushort4 a0 = *(const ushort4*)&r0a[h];
    ushort4 b0 = *(const ushort4*)&r0b[h];
    ushort4 a1 = *(const ushort4*)&r1a[h];
    ushort4 b1 = *(const ushort4*)&r1b[h];
    float4 o4;
    o4.x = g0 * (bf2f(a0.x) + bf2f(b0.x)) + g1 * (bf2f(a1.x) + bf2f(b1.x));
    o4.y = g0 * (bf2f(a0.y) + bf2f(b0.y)) + g1 * (bf2f(a1.y) + bf2f(b1.y));
    o4.z = g0 * (bf2f(a0.z) + bf2f(b0.z)) + g1 * (bf2f(a1.z) + bf2f(b1.z));
    o4.w = g0 * (bf2f(a0.w) + bf2f(b0.w)) + g1 * (bf2f(a1.w) + bf2f(b1.w));
    *(float4*)&o[h] = o4;
  }
}

// -------------------------------- launch ---------------------------------------
extern "C" void kernel_launch(void* const* d_in, const int* in_sizes, int n_in,
                              void* d_out, int out_size, void* d_ws, size_t ws_size,
                              hipStream_t stream)
{
  (void)in_sizes; (void)n_in; (void)ws_size; (void)out_size;
  const float* x  = (const float*)d_in[0];
  const float* rw = (const float*)d_in[1];
  const float* rb = (const float*)d_in[2];
  const float* w1 = (const float*)d_in[3];
  const float* b1 = (const float*)d_in[4];
  const float* w2 = (const float*)d_in[5];
  const float* b2 = (const float*)d_in[6];
  float* out = (float*)d_out;

  char* ws = (char*)d_ws;
  size_t off = 0;
  auto alloc = [&](size_t bytes) {
    off = (off + 255) & ~(size_t)255;
    void* p = ws + off;
    off += bytes;
    return p;
  };
  unsigned short* xb  = (unsigned short*)alloc((size_t)TOK * HD * 2);
  unsigned short* w1t = (unsigned short*)alloc((size_t)E_EXP * FD * HD * 2);
  unsigned short* w2t = (unsigned short*)alloc((size_t)E_EXP * HD * FD * 2);
  unsigned short* h1  = (unsigned short*)alloc((size_t)CAP * FD * 2);
  unsigned short* h2  = (unsigned short*)alloc((size_t)2 * CAP * HD * 2);  // 2 k-partials
  int*   token_list = (int*)alloc(CAP * 4);
  int*   pos_list   = (int*)alloc((size_t)TOK * 2 * 4);
  int*   ids        = (int*)alloc((size_t)TOK * 2 * 4);
  float* gates      = (float*)alloc((size_t)TOK * 2 * 4);
  float* probs      = (float*)alloc((size_t)TOK * 8 * 4);
  int*   meta       = (int*)alloc(1024 * 4);
  char*  ctrl       = (char*)token_list;
  size_t ctrl_bytes = (ws + off) - ctrl;

  hipMemsetAsync(ctrl, 0, ctrl_bytes, stream);

  router_kernel<<<TOK / 4, 256, 0, stream>>>(x, rw, rb, xb, probs, ids, gates);
  transpose_kernel<<<W1_TILES + W2_TILES, 256, 0, stream>>>(w1, w1t, w2, w2t);
  stats_kernel<<<1, 256, 0, stream>>>(ids, probs, meta, out + (size_t)TOK * HD);
  scatter_kernel<<<TOK / 256, 256, 0, stream>>>(ids, meta, token_list, pos_list);
  // GEMM1: 71 max m-tiles x 24 n-tiles, 4-wave blocks (64x64 per wave, m97 shape)
  moe_gemm<128, 128, 0, 4, 1><<<71 * (FD / 128), 256, 0, stream>>>(
      xb, w1t, b1, token_list, meta, h1, HD, FD);
  // GEMM2: 71 max m-tiles x 6 n-tiles x 2 k-splits, same 128x128 4-wave shape
  moe_gemm<128, 128, 1, 4, 2><<<71 * (HD / 128) * 2, 256, 0, stream>>>(
      h1, w2t, b2, token_list, meta, h2, FD, HD);
  combine_kernel<<<TOK / 4, 256, 0, stream>>>(h2, pos_list, gates, out);
}